// Round 1
// baseline (7719.243 us; speedup 1.0000x reference)
//
#include <hip/hip_runtime.h>

#define DI __device__ __forceinline__

typedef float f32x4 __attribute__((ext_vector_type(4)));
typedef __bf16 bf16x8 __attribute__((ext_vector_type(8)));
typedef __bf16 bf16x4 __attribute__((ext_vector_type(4)));

static DI f32x4 mfma_bf16(bf16x8 a, bf16x8 b, f32x4 c) {
    return __builtin_amdgcn_mfma_f32_16x16x32_bf16(a, b, c, 0, 0, 0);
}
static DI bf16x8 ldb8(const __bf16* p) { return *(const bf16x8*)p; }
static DI float sigf(float x) { return 1.0f / (1.0f + expf(-x)); }

// sc1 coherent (write-through to memory-side cache) stores; relaxed agent atomics.
static DI void stc_u32(void* p, unsigned v) {
    __hip_atomic_store((unsigned*)p, v, __ATOMIC_RELAXED, __HIP_MEMORY_SCOPE_AGENT);
}
static DI void stc_u16(void* p, unsigned short v) {
    __hip_atomic_store((unsigned short*)p, v, __ATOMIC_RELAXED, __HIP_MEMORY_SCOPE_AGENT);
}
static DI void stc_bf16(__bf16* p, float v) {
    union { __bf16 b; unsigned short s; } c; c.b = (__bf16)v;
    stc_u16(p, c.s);
}

// B=64, T=32, R=49, LOCAL=1024, QVEC=512, EMB=256, HID=512, VOCAB=10000
#define GRID_BLKS 64

// ---------------- RMW-free distributed flag barrier ----------------
// Arrival: ONE sc1 store to own flag. Detection: wave 0 polls flags, one/lane.
// __syncthreads() before the flag store drains this block's sc1 data stores
// (vmcnt(0)) so data is at the coherence point before the flag is visible.
static DI void gbar_all(unsigned* FL, int blk, unsigned tgt) {
    __syncthreads();
    if (threadIdx.x < 64) {
        if (threadIdx.x == 0)
            __hip_atomic_store(&FL[blk], tgt, __ATOMIC_RELAXED, __HIP_MEMORY_SCOPE_AGENT);
        for (;;) {
            unsigned f = __hip_atomic_load(&FL[threadIdx.x], __ATOMIC_RELAXED,
                                           __HIP_MEMORY_SCOPE_AGENT);
            if (__all(f >= tgt)) break;
            __builtin_amdgcn_s_sleep(1);
        }
    }
    __syncthreads();
}

// Barrier where only blocks 0..15 produce data: they arrive, everyone waits on
// their 16 flags only. Safe by transitivity: BC flags are stored only after BC
// blocks observed ALL 64 phase-A flags (data drained to the MALL coherence
// point), and all consumer loads use fresh (never-cached) slot addresses.
static DI void gbar16(unsigned* FL, int blk, unsigned tgt) {
    __syncthreads();
    if (threadIdx.x < 64) {
        if (threadIdx.x == 0 && blk < 16)
            __hip_atomic_store(&FL[blk], tgt, __ATOMIC_RELAXED, __HIP_MEMORY_SCOPE_AGENT);
        for (;;) {
            unsigned f = (threadIdx.x < 16)
                ? __hip_atomic_load(&FL[threadIdx.x], __ATOMIC_RELAXED,
                                    __HIP_MEMORY_SCOPE_AGENT)
                : tgt;
            if (__all(f >= tgt)) break;
            __builtin_amdgcn_s_sleep(1);
        }
    }
    __syncthreads();
}

// ---------------- conversions + gathers (z-dispatched) ----------------
__global__ void convert_kernel(
    const float* Wih, const float* Whh,
    const float* bih, const float* bhh, const float* Wu,
    const float* emb, const int* answers, const float* localf,
    __bf16* WGo, float* biasg, __bf16* WUo, __bf16* Yo, __bf16* LFo)
{
    int z = blockIdx.z;
    int stride = gridDim.x * blockDim.x;
    int tid0 = blockIdx.x * blockDim.x + threadIdx.x;
    if (z == 0) {
        // Gate-permuted concat [W_ih | W_hh] -> WG [2048 perm rows, 1280]
        // perm row n <-> original row r = (n&3)*512 + (n>>2)  (unit-major)
        const int N = 2048 * 1280;
        for (int i = tid0; i < N; i += stride) {
            int n = i / 1280, k = i - n * 1280;
            int r = (n & 3) * 512 + (n >> 2);
            float val = (k < 768) ? Wih[r * 768 + k] : Whh[r * 512 + (k - 768)];
            WGo[i] = (__bf16)val;
        }
        for (int n = tid0; n < 2048; n += stride) {
            int r = (n & 3) * 512 + (n >> 2);
            biasg[n] = bih[r] + bhh[r];
        }
    } else if (z == 1) {
        const int N = 512 * 1536;
        for (int i = tid0; i < N; i += stride) WUo[i] = (__bf16)Wu[i];
    } else if (z == 2) {
        // y_seq gather: t=0 -> emb[1]; t>=1 -> emb[answers[b, t-1]]   [32,64,256]
        const int N = 32 * 64 * 256;
        for (int i = tid0; i < N; i += stride) {
            int t = i >> 14;
            int b = (i >> 8) & 63;
            int e = i & 255;
            int tok = (t == 0) ? 1 : answers[b * 32 + (t - 1)];
            Yo[i] = (__bf16)emb[tok * 256 + e];
        }
    } else {
        const int N = 64 * 49 * 1024;
        for (int i = tid0; i < N; i += stride) LFo[i] = (__bf16)localf[i];
    }
}

// ---------------- init: h0 = q@Wh^T, c0 = q@Wc^T, o0 = g@Wg2o^T + b ----------------
__global__ void init_kernel(
    const float* q, const float* g,
    const float* Wh, const float* Wc, const float* Wg2o, const float* bg2o,
    __bf16* h0b, float* c0f, __bf16* o0b)
{
    int z = blockIdx.z;
    const float* A; const float* B; int K;
    if (z == 0)      { A = q; B = Wh;   K = 512; }
    else if (z == 1) { A = q; B = Wc;   K = 512; }
    else             { A = g; B = Wg2o; K = 2048; }
    int n0 = blockIdx.x * 64, m0 = blockIdx.y * 16;
    __shared__ float As[32][16];
    __shared__ float Bs[32][64];
    int tid = threadIdx.x;
    int n = tid & 63, tyq = tid >> 6;
    float acc[4] = {0.f, 0.f, 0.f, 0.f};
    for (int k0 = 0; k0 < K; k0 += 32) {
        {
            int idx = tid * 2, row = idx >> 5, kk = idx & 31;
            const float* ar = A + (m0 + row) * K + k0 + kk;
            As[kk][row] = ar[0];
            As[kk + 1][row] = ar[1];
        }
        {
            int row = tid >> 2, kk = (tid & 3) * 8;
            const float* br = B + (n0 + row) * K + k0 + kk;
            float4 v0 = *(const float4*)br;
            float4 v1 = *(const float4*)(br + 4);
            Bs[kk + 0][row] = v0.x; Bs[kk + 1][row] = v0.y;
            Bs[kk + 2][row] = v0.z; Bs[kk + 3][row] = v0.w;
            Bs[kk + 4][row] = v1.x; Bs[kk + 5][row] = v1.y;
            Bs[kk + 6][row] = v1.z; Bs[kk + 7][row] = v1.w;
        }
        __syncthreads();
        #pragma unroll
        for (int k = 0; k < 32; k++) {
            float4 a = *(const float4*)&As[k][tyq * 4];
            float b = Bs[k][n];
            acc[0] += a.x * b; acc[1] += a.y * b; acc[2] += a.z * b; acc[3] += a.w * b;
        }
        __syncthreads();
    }
    int ng = n0 + n;
    #pragma unroll
    for (int i = 0; i < 4; i++) {
        int m = m0 + tyq * 4 + i;
        float v = acc[i];
        if (z == 0)      { h0b[m * 512 + ng] = (__bf16)v; }
        else if (z == 1) { c0f[m * 512 + ng] = v; }
        else             { o0b[m * 512 + ng] = (__bf16)(v + bg2o[ng]); }
    }
}

// ---------------- attn_proj = localf @ W_attn^T -> bf16 [3136,512], MFMA ----------------
__global__ __launch_bounds__(256) void attnproj_kernel(
    const float* Af, const float* Bf, __bf16* APo)
{
    __shared__ __bf16 As[64][72];
    __shared__ __bf16 Bs[64][72];
    int tid = threadIdx.x;
    int m0 = blockIdx.x * 64, n0 = blockIdx.y * 64;
    int w = tid >> 6, lane = tid & 63, row16 = lane & 15, kg = lane >> 4;
    f32x4 acc[4] = {};
    for (int k0 = 0; k0 < 1024; k0 += 64) {
        int r = tid >> 2, col = (tid & 3) * 16;
        const float* ap = Af + (size_t)(m0 + r) * 1024 + k0 + col;
        const float* bp = Bf + (size_t)(n0 + r) * 1024 + k0 + col;
        bf16x8 va0, va1, vb0, vb1;
        #pragma unroll
        for (int u = 0; u < 8; u++) {
            va0[u] = (__bf16)ap[u]; va1[u] = (__bf16)ap[u + 8];
            vb0[u] = (__bf16)bp[u]; vb1[u] = (__bf16)bp[u + 8];
        }
        *(bf16x8*)&As[r][col] = va0; *(bf16x8*)&As[r][col + 8] = va1;
        *(bf16x8*)&Bs[r][col] = vb0; *(bf16x8*)&Bs[r][col + 8] = vb1;
        __syncthreads();
        #pragma unroll
        for (int kt = 0; kt < 2; kt++) {
            bf16x8 af = *(const bf16x8*)&As[w * 16 + row16][kt * 32 + kg * 8];
            #pragma unroll
            for (int j = 0; j < 4; j++) {
                bf16x8 bfv = *(const bf16x8*)&Bs[j * 16 + row16][kt * 32 + kg * 8];
                acc[j] = mfma_bf16(af, bfv, acc[j]);
            }
        }
        __syncthreads();
    }
    #pragma unroll
    for (int j = 0; j < 4; j++)
        #pragma unroll
        for (int r = 0; r < 4; r++)
            APo[(size_t)(m0 + w * 16 + kg * 4 + r) * 512 + n0 + j * 16 + row16] =
                (__bf16)acc[j][r];
}

// ---------------- persistent step-loop kernel (grid = 64 blocks) ----------------
// 2 phases/step (was 3):
//  A: all 64 blocks, unit-partitioned gates GEMM + LSTM pointwise -> h (sc1).
//     o/h A-operand MALL loads preloaded into a 32-quad register array for MLP.
//  BC: 16 blocks x 4 batches (wave = batch): attention (in-register softmax)
//     and o = tanh([a|h]@Wu^T+bu) as a padded-m MFMA GEMM from a swizzled LDS
//     tile. a/h stay block-local -> no AS buffer, no MALL A-operand reads.
__global__ __launch_bounds__(256, 1) void loop_kernel(
    const __bf16* Yall, const __bf16* WG, const float* BG,
    const __bf16* WU, const float* bu,
    const __bf16* APb, const __bf16* LFb, const float* CF0,
    __bf16* OS, __bf16* HS, unsigned* FL)
{
    __shared__ float S[64][33];
    __shared__ float Cs[64][8];
    // BC A-tile: 16 rows x 1536 bf16 (rows 0..3 = [a|h] of the 4 batches,
    // rows 4..15 zero). Row stride 3072 B, XOR-swizzled 16B granules
    // (byte ^= (row&7)<<4) to kill the 16-way column bank conflict.
    __shared__ __bf16 Asb[16 * 1536];
    int tid = threadIdx.x;
    int blk = blockIdx.x;
    int w = tid >> 6, lane = tid & 63, row16 = lane & 15, kg = lane >> 4;

    // zero pad rows of the BC A-tile (once)
    {
        bf16x8 z = {};
        for (int i = tid; i < (12 * 1536) / 8; i += 256)
            ((bf16x8*)(Asb + 4 * 1536))[i] = z;
    }
    // load c0 slice (units [8*blk, 8*blk+8)) into LDS — block-local forever
    {
        int b = tid >> 2, u0 = (tid & 3) * 2;
        Cs[b][u0]     = CF0[b * 512 + blk * 8 + u0];
        Cs[b][u0 + 1] = CF0[b * 512 + blk * 8 + u0 + 1];
    }
    __syncthreads();

    for (int t = 0; t < 32; t++) {
        // ---- Phase A: gates = [y|o|h] @ WG^T (wave = 16-batch m-tile, full K),
        //      LSTM pointwise -> h (sc1 to HS[t+1]), c (LDS) ----
        {
            const __bf16* Yt = Yall + t * 16384;
            const __bf16* Op = OS + t * 32768;
            const __bf16* Hp = HS + t * 32768;
            int arow = w * 16 + row16;
            // preload the MALL-latency o/h A-operand: 32 quads in flight at once
            bf16x8 a_o[16], a_h[16];
            #pragma unroll
            for (int kt = 0; kt < 16; kt++)
                a_o[kt] = ldb8(Op + arow * 512 + kt * 32 + kg * 8);
            #pragma unroll
            for (int kt = 0; kt < 16; kt++)
                a_h[kt] = ldb8(Hp + arow * 512 + kt * 32 + kg * 8);
            int n0 = blk * 32;
            f32x4 acc[2] = {};
            #pragma unroll
            for (int kt = 0; kt < 40; kt++) {
                int k0 = kt * 32;
                bf16x8 af;
                if (kt < 8)       af = ldb8(Yt + arow * 256 + k0 + kg * 8);
                else if (kt < 24) af = a_o[kt - 8];
                else              af = a_h[kt - 24];
                #pragma unroll
                for (int nt = 0; nt < 2; nt++) {
                    bf16x8 bfv = ldb8(WG + (size_t)(n0 + nt * 16 + row16) * 1280 + k0 + kg * 8);
                    acc[nt] = mfma_bf16(af, bfv, acc[nt]);
                }
            }
            #pragma unroll
            for (int nt = 0; nt < 2; nt++)
                #pragma unroll
                for (int r = 0; r < 4; r++)
                    S[w * 16 + kg * 4 + r][nt * 16 + row16] = acc[nt][r];
            __syncthreads();
            {
                int b = tid >> 2, u0 = (tid & 3) * 2;
                float h2[2];
                #pragma unroll
                for (int uu = 0; uu < 2; uu++) {
                    int u = u0 + uu;
                    float gi = S[b][u * 4 + 0] + BG[n0 + u * 4 + 0];
                    float gf = S[b][u * 4 + 1] + BG[n0 + u * 4 + 1];
                    float gg = S[b][u * 4 + 2] + BG[n0 + u * 4 + 2];
                    float go = S[b][u * 4 + 3] + BG[n0 + u * 4 + 3];
                    float cp = Cs[b][u];
                    float cn = sigf(gf) * cp + sigf(gi) * tanhf(gg);
                    h2[uu] = sigf(go) * tanhf(cn);
                    Cs[b][u] = cn;
                }
                union { __bf16 h[2]; unsigned v; } pk;
                pk.h[0] = (__bf16)h2[0]; pk.h[1] = (__bf16)h2[1];
                stc_u32((unsigned*)(HS + (t + 1) * 32768 + b * 512 + blk * 8 + u0), pk.v);
            }
        }
        gbar_all(FL, blk, 2 * t + 1);

        // ---- Phase BC (blocks 0..15, wave = batch b = blk*4 + w):
        //      attention + o = tanh([a|h]@Wu^T + bu) ----
        if (blk < 16) {
            int b = blk * 4 + w;
            const __bf16* hb = HS + (t + 1) * 32768 + b * 512;
            bf16x8 h8 = ldb8(hb + lane * 8);
            // e[r] = attn_proj[b][r] . h   (in-register capture: lane r keeps e[r])
            float ev = -3.0e38f;
            #pragma unroll 4
            for (int r = 0; r < 49; r++) {
                bf16x8 ap8 = ldb8(APb + (size_t)(b * 49 + r) * 512 + lane * 8);
                float s = 0.f;
                #pragma unroll
                for (int u = 0; u < 8; u++) s += (float)ap8[u] * (float)h8[u];
                #pragma unroll
                for (int off = 32; off > 0; off >>= 1) s += __shfl_xor(s, off);
                ev = (lane == r) ? s : ev;
            }
            // in-register wave softmax over 49 rows
            float mx = ev;
            #pragma unroll
            for (int off = 32; off > 0; off >>= 1) mx = fmaxf(mx, __shfl_xor(mx, off));
            float ex = (lane < 49) ? expf(ev - mx) : 0.0f;
            float sm = ex;
            #pragma unroll
            for (int off = 32; off > 0; off >>= 1) sm += __shfl_xor(sm, off);
            float att = ex / sm;   // lanes >= 49 hold 0
            // a = sum_r att[r] * LF[b][r][:]   (16 features/lane)
            float av[16];
            #pragma unroll
            for (int u = 0; u < 16; u++) av[u] = 0.f;
            const __bf16* lb = LFb + (size_t)b * 49 * 1024 + lane * 16;
            #pragma unroll 4
            for (int r = 0; r < 49; r++) {
                float wt = __shfl(att, r);
                bf16x8 l0 = ldb8(lb + r * 1024);
                bf16x8 l1 = ldb8(lb + r * 1024 + 8);
                #pragma unroll
                for (int u = 0; u < 8; u++) {
                    av[u] += wt * (float)l0[u];
                    av[u + 8] += wt * (float)l1[u];
                }
            }
            // write [a|h] into swizzled A-tile row w
            {
                bf16x8 p0, p1;
                #pragma unroll
                for (int u = 0; u < 8; u++) { p0[u] = (__bf16)av[u]; p1[u] = (__bf16)av[u + 8]; }
                int swz = (w & 7) << 4;
                *(bf16x8*)((char*)Asb + w * 3072 + ((lane * 32) ^ swz)) = p0;
                *(bf16x8*)((char*)Asb + w * 3072 + ((lane * 32 + 16) ^ swz)) = p1;
                *(bf16x8*)((char*)Asb + w * 3072 + ((2048 + lane * 16) ^ swz)) = h8;
            }
            __syncthreads();
            // o GEMM: [16(pad), 1536] @ WU^T, wave w -> n in [w*128, w*128+128)
            float bun[8];
            if (lane < 16) {
                #pragma unroll
                for (int nt = 0; nt < 8; nt++) bun[nt] = bu[w * 128 + nt * 16 + lane];
            }
            f32x4 acc8[8] = {};
            int rswz = (row16 & 7) << 4;
            #pragma unroll
            for (int kt = 0; kt < 48; kt++) {
                bf16x8 afr = *(const bf16x8*)((const char*)Asb + row16 * 3072 +
                                              ((kt * 64 + kg * 16) ^ rswz));
                #pragma unroll
                for (int nt = 0; nt < 8; nt++) {
                    bf16x8 bv = ldb8(WU + (size_t)(w * 128 + nt * 16 + row16) * 1536 +
                                     kt * 32 + kg * 8);
                    acc8[nt] = mfma_bf16(afr, bv, acc8[nt]);
                }
            }
            if (lane < 16) {
                __bf16* Oo = OS + (t + 1) * 32768;
                #pragma unroll
                for (int nt = 0; nt < 8; nt++) {
                    int n = w * 128 + nt * 16 + lane;
                    #pragma unroll
                    for (int r = 0; r < 4; r++)   // C row r = batch blk*4 + r
                        stc_bf16(&Oo[(blk * 4 + r) * 512 + n], tanhf(acc8[nt][r] + bun[nt]));
                }
            }
        }
        gbar16(FL, blk, 2 * t + 2);
    }
}

// ---------------- vocab: logits = O @ Wv^T + b, 128x128 LDS-tiled MFMA ----------------
// B operand converted f32 -> bf16 during LDS staging (no WV buffer needed).
__global__ __launch_bounds__(256) void vocab_kernel(
    const __bf16* A, const float* Wv, const float* bv, float* out)
{
    __shared__ __bf16 As[128][72];
    __shared__ __bf16 Bs[128][72];
    int tid = threadIdx.x;
    int m0 = blockIdx.x * 128;   // 16 mblk
    int n0 = blockIdx.y * 128;   // 79 nblk
    int w = tid >> 6, lane = tid & 63, row16 = lane & 15, kg = lane >> 4;
    int mw = (w & 1) * 64, nw = (w >> 1) * 64;
    f32x4 acc[4][4] = {};
    for (int k0 = 0; k0 < 512; k0 += 64) {
        #pragma unroll
        for (int q = 0; q < 2; q++) {
            int c = q * 256 + tid;
            int r = c >> 2, col = (c & 3) * 16;
            bf16x8 v0 = ldb8(A + (size_t)(m0 + r) * 512 + k0 + col);
            bf16x8 v1 = ldb8(A + (size_t)(m0 + r) * 512 + k0 + col + 8);
            *(bf16x8*)&As[r][col] = v0;
            *(bf16x8*)&As[r][col + 8] = v1;
            bf16x8 u0, u1;
            int nrow = n0 + r;
            if (nrow < 10000) {
                const float* bp = Wv + (size_t)nrow * 512 + k0 + col;
                #pragma unroll
                for (int u = 0; u < 8; u++) {
                    u0[u] = (__bf16)bp[u];
                    u1[u] = (__bf16)bp[u + 8];
                }
            } else {
                u0 = (bf16x8)(__bf16)0.0f;
                u1 = (bf16x8)(__bf16)0.0f;
            }
            *(bf16x8*)&Bs[r][col] = u0;
            *(bf16x8*)&Bs[r][col + 8] = u1;
        }
        __syncthreads();
        #pragma unroll
        for (int kt = 0; kt < 2; kt++) {
            bf16x8 af[4], bfr[4];
            #pragma unroll
            for (int i = 0; i < 4; i++)
                af[i] = *(const bf16x8*)&As[mw + i * 16 + row16][kt * 32 + kg * 8];
            #pragma unroll
            for (int j = 0; j < 4; j++)
                bfr[j] = *(const bf16x8*)&Bs[nw + j * 16 + row16][kt * 32 + kg * 8];
            #pragma unroll
            for (int i = 0; i < 4; i++)
                #pragma unroll
                for (int j = 0; j < 4; j++)
                    acc[i][j] = mfma_bf16(af[i], bfr[j], acc[i][j]);
        }
        __syncthreads();
    }
    #pragma unroll
    for (int j = 0; j < 4; j++) {
        int n = n0 + nw + j * 16 + row16;
        if (n < 10000) {
            float bvn = bv[n];
            #pragma unroll
            for (int i = 0; i < 4; i++) {
                #pragma unroll
                for (int r = 0; r < 4; r++) {
                    int m = m0 + mw + i * 16 + kg * 4 + r;   // m = t*64 + b
                    int tt = m >> 6, b = m & 63;
                    out[(size_t)(b * 32 + tt) * 10000 + n] = acc[i][j][r] + bvn;
                }
            }
        }
    }
}

extern "C" void kernel_launch(void* const* d_in, const int* in_sizes, int n_in,
                              void* d_out, int out_size, void* d_ws, size_t ws_size,
                              hipStream_t stream) {
    (void)in_sizes; (void)n_in; (void)out_size; (void)ws_size;
    const float* localf  = (const float*)d_in[0];
    const float* globalf = (const float*)d_in[1];
    const float* qvec    = (const float*)d_in[2];
    const int*   answers = (const int*)d_in[3];
    const float* emb     = (const float*)d_in[4];
    const float* Wg2o    = (const float*)d_in[5];
    const float* bg2o    = (const float*)d_in[6];
    const float* Wh      = (const float*)d_in[7];
    const float* Wc      = (const float*)d_in[8];
    const float* Wih     = (const float*)d_in[9];
    const float* Whh     = (const float*)d_in[10];
    const float* bih     = (const float*)d_in[11];
    const float* bhh     = (const float*)d_in[12];
    const float* Wattn   = (const float*)d_in[13];
    const float* Wu      = (const float*)d_in[14];
    const float* bu      = (const float*)d_in[15];
    const float* Wvocab  = (const float*)d_in[16];
    const float* bvocab  = (const float*)d_in[17];
    float* out = (float*)d_out;

    char* ws = (char*)d_ws;
    __bf16* WG  = (__bf16*)(ws + 0);          // 2048*1280 bf16 (gate-perm [W_ih|W_hh])   5,242,880
    __bf16* WU  = (__bf16*)(ws + 5242880);    // 512*1536 bf16                            1,572,864
    __bf16* Y   = (__bf16*)(ws + 6815744);    // 32*64*256 bf16                           1,048,576
    float*  BG  = (float*) (ws + 7864320);    // 2048 f32 (b_ih+b_hh perm)                    8,192
    __bf16* OS  = (__bf16*)(ws + 7872512);    // 33 slots * 64*512 bf16 (o; slot0=o0)     2,162,688
    __bf16* HS  = (__bf16*)(ws + 10035200);   // 33 slots * 64*512 bf16 (h; slot0=h0)     2,162,688
    // (former AS region 12197888..16523263 now unused — a is block-local)
    float*  CF0 = (float*) (ws + 16523264);   // 64*512 f32 (c0)                            131,072
    __bf16* APb = (__bf16*)(ws + 16654336);   // 64*49*512 bf16 (attn_proj)               3,211,264
    __bf16* LFb = (__bf16*)(ws + 19865600);   // 64*49*1024 bf16 (local features)         6,422,528
    unsigned* FL = (unsigned*)(ws + 26288128); // 64 u32 flags                                 256
    // total: 26,288,384 B  (within r1-verified >=27.5MB workspace)

    hipMemsetAsync(FL, 0, 256, stream);
    convert_kernel<<<dim3(1024, 1, 4), 256, 0, stream>>>(
        Wih, Whh, bih, bhh, Wu, emb, answers, localf,
        WG, BG, WU, Y, LFb);
    init_kernel<<<dim3(8, 4, 3), 256, 0, stream>>>(
        qvec, globalf, Wh, Wc, Wg2o, bg2o, HS, CF0, OS);
    attnproj_kernel<<<dim3(49, 8), 256, 0, stream>>>(localf, Wattn, APb);
    loop_kernel<<<GRID_BLKS, 256, 0, stream>>>(
        Y, WG, BG, WU, bu, APb, LFb, CF0, OS, HS, FL);
    vocab_kernel<<<dim3(16, 79), 256, 0, stream>>>(OS + 32768, Wvocab, bvocab, out);
}

// Round 2
// 1448.226 us; speedup vs baseline: 5.3301x; 5.3301x over previous
//
#include <hip/hip_runtime.h>

#define DI __device__ __forceinline__

typedef float f32x4 __attribute__((ext_vector_type(4)));
typedef __bf16 bf16x8 __attribute__((ext_vector_type(8)));
typedef __bf16 bf16x4 __attribute__((ext_vector_type(4)));

static DI f32x4 mfma_bf16(bf16x8 a, bf16x8 b, f32x4 c) {
    return __builtin_amdgcn_mfma_f32_16x16x32_bf16(a, b, c, 0, 0, 0);
}
static DI bf16x8 ldb8(const __bf16* p) { return *(const bf16x8*)p; }
static DI float sigf(float x) { return 1.0f / (1.0f + expf(-x)); }

// sc1 coherent (write-through to memory-side cache) stores; relaxed agent atomics.
static DI void stc_u32(void* p, unsigned v) {
    __hip_atomic_store((unsigned*)p, v, __ATOMIC_RELAXED, __HIP_MEMORY_SCOPE_AGENT);
}
static DI void stc_u64(void* p, unsigned long long v) {
    __hip_atomic_store((unsigned long long*)p, v, __ATOMIC_RELAXED, __HIP_MEMORY_SCOPE_AGENT);
}
static DI unsigned long long ldc_u64(void* p) {
    return __hip_atomic_load((unsigned long long*)p, __ATOMIC_RELAXED, __HIP_MEMORY_SCOPE_AGENT);
}
static DI void stc_u16(void* p, unsigned short v) {
    __hip_atomic_store((unsigned short*)p, v, __ATOMIC_RELAXED, __HIP_MEMORY_SCOPE_AGENT);
}

// B=64, T=32, R=49, LOCAL=1024, QVEC=512, EMB=256, HID=512, VOCAB=10000
#define GRID_BLKS 64

// ---------------- RMW-free distributed flag barrier ----------------
// Arrival: ONE sc1 store to own flag. Detection: wave 0 polls all 64 flags,
// one per lane. __syncthreads() before the flag store drains this block's sc1
// data stores (vmcnt(0)) so data is at the coherence point before the flag.
static DI void gbar_all(unsigned* FL, int blk, unsigned tgt) {
    __syncthreads();
    if (threadIdx.x < 64) {
        if (threadIdx.x == 0)
            __hip_atomic_store(&FL[blk], tgt, __ATOMIC_RELAXED, __HIP_MEMORY_SCOPE_AGENT);
        for (;;) {
            unsigned f = __hip_atomic_load(&FL[threadIdx.x], __ATOMIC_RELAXED,
                                           __HIP_MEMORY_SCOPE_AGENT);
            if (__all(f >= tgt)) break;
            __builtin_amdgcn_s_sleep(1);
        }
    }
    __syncthreads();
}

// ---------------- conversions + gathers (z-dispatched) ----------------
__global__ void convert_kernel(
    const float* Wih, const float* Whh,
    const float* bih, const float* bhh, const float* Wu,
    const float* emb, const int* answers,
    __bf16* WGo, float* biasg, __bf16* WhTo, __bf16* Yo)
{
    int z = blockIdx.z;
    int stride = gridDim.x * blockDim.x;
    int tid0 = blockIdx.x * blockDim.x + threadIdx.x;
    if (z == 0) {
        // Gate-permuted concat [W_ih | W_hh] -> WG [2048 perm rows, 1280]
        // perm row n <-> original row r = (n&3)*512 + (n>>2)  (unit-major)
        const int N = 2048 * 1280;
        for (int i = tid0; i < N; i += stride) {
            int n = i / 1280, k = i - n * 1280;
            int r = (n & 3) * 512 + (n >> 2);
            float val = (k < 768) ? Wih[r * 768 + k] : Whh[r * 512 + (k - 768)];
            WGo[i] = (__bf16)val;
        }
        for (int n = tid0; n < 2048; n += stride) {
            int r = (n & 3) * 512 + (n >> 2);
            biasg[n] = bih[r] + bhh[r];
        }
    } else if (z == 1) {
        // Wu_hT [512 k][512 u] = Wu[u][1024 + k]  (h-part of W_u, transposed)
        const int N = 512 * 512;
        for (int i = tid0; i < N; i += stride) {
            int k = i >> 9, u = i & 511;
            WhTo[i] = (__bf16)Wu[(size_t)u * 1536 + 1024 + k];
        }
    } else {
        // y_seq gather: t=0 -> emb[1]; t>=1 -> emb[answers[b, t-1]]   [32,64,256]
        const int N = 32 * 64 * 256;
        for (int i = tid0; i < N; i += stride) {
            int t = i >> 14;
            int b = (i >> 8) & 63;
            int e = i & 255;
            int tok = (t == 0) ? 1 : answers[b * 32 + (t - 1)];
            Yo[i] = (__bf16)emb[tok * 256 + e];
        }
    }
}

// ---------------- init: h0 = q@Wh^T, c0 = q@Wc^T, o0 = g@Wg2o^T + b ----------------
__global__ void init_kernel(
    const float* q, const float* g,
    const float* Wh, const float* Wc, const float* Wg2o, const float* bg2o,
    __bf16* h0b, float* c0f, __bf16* o0b)
{
    int z = blockIdx.z;
    const float* A; const float* B; int K;
    if (z == 0)      { A = q; B = Wh;   K = 512; }
    else if (z == 1) { A = q; B = Wc;   K = 512; }
    else             { A = g; B = Wg2o; K = 2048; }
    int n0 = blockIdx.x * 64, m0 = blockIdx.y * 16;
    __shared__ float As[32][16];
    __shared__ float Bs[32][64];
    int tid = threadIdx.x;
    int n = tid & 63, tyq = tid >> 6;
    float acc[4] = {0.f, 0.f, 0.f, 0.f};
    for (int k0 = 0; k0 < K; k0 += 32) {
        {
            int idx = tid * 2, row = idx >> 5, kk = idx & 31;
            const float* ar = A + (m0 + row) * K + k0 + kk;
            As[kk][row] = ar[0];
            As[kk + 1][row] = ar[1];
        }
        {
            int row = tid >> 2, kk = (tid & 3) * 8;
            const float* br = B + (n0 + row) * K + k0 + kk;
            float4 v0 = *(const float4*)br;
            float4 v1 = *(const float4*)(br + 4);
            Bs[kk + 0][row] = v0.x; Bs[kk + 1][row] = v0.y;
            Bs[kk + 2][row] = v0.z; Bs[kk + 3][row] = v0.w;
            Bs[kk + 4][row] = v1.x; Bs[kk + 5][row] = v1.y;
            Bs[kk + 6][row] = v1.z; Bs[kk + 7][row] = v1.w;
        }
        __syncthreads();
        #pragma unroll
        for (int k = 0; k < 32; k++) {
            float4 a = *(const float4*)&As[k][tyq * 4];
            float b = Bs[k][n];
            acc[0] += a.x * b; acc[1] += a.y * b; acc[2] += a.z * b; acc[3] += a.w * b;
        }
        __syncthreads();
    }
    int ng = n0 + n;
    #pragma unroll
    for (int i = 0; i < 4; i++) {
        int m = m0 + tyq * 4 + i;
        float v = acc[i];
        if (z == 0)      { h0b[m * 512 + ng] = (__bf16)v; }
        else if (z == 1) { c0f[m * 512 + ng] = v; }
        else             { o0b[m * 512 + ng] = (__bf16)(v + bg2o[ng]); }
    }
}

// ------- proj: out[3136,512] = LF[3136,1024] @ B^T (B rows stride ldb), MFMA -------
// Used twice: AP = LF @ W_attn^T (ldb=1024), LU = LF @ Wu_a^T (ldb=1536, a-part cols).
__global__ __launch_bounds__(256) void attnproj_kernel(
    const float* Af, const float* Bf, int ldb, __bf16* APo)
{
    __shared__ __bf16 As[64][72];
    __shared__ __bf16 Bs[64][72];
    int tid = threadIdx.x;
    int m0 = blockIdx.x * 64, n0 = blockIdx.y * 64;
    int w = tid >> 6, lane = tid & 63, row16 = lane & 15, kg = lane >> 4;
    f32x4 acc[4] = {};
    for (int k0 = 0; k0 < 1024; k0 += 64) {
        int r = tid >> 2, col = (tid & 3) * 16;
        const float* ap = Af + (size_t)(m0 + r) * 1024 + k0 + col;
        const float* bp = Bf + (size_t)(n0 + r) * ldb + k0 + col;
        bf16x8 va0, va1, vb0, vb1;
        #pragma unroll
        for (int u = 0; u < 8; u++) {
            va0[u] = (__bf16)ap[u]; va1[u] = (__bf16)ap[u + 8];
            vb0[u] = (__bf16)bp[u]; vb1[u] = (__bf16)bp[u + 8];
        }
        *(bf16x8*)&As[r][col] = va0; *(bf16x8*)&As[r][col + 8] = va1;
        *(bf16x8*)&Bs[r][col] = vb0; *(bf16x8*)&Bs[r][col + 8] = vb1;
        __syncthreads();
        #pragma unroll
        for (int kt = 0; kt < 2; kt++) {
            bf16x8 af = *(const bf16x8*)&As[w * 16 + row16][kt * 32 + kg * 8];
            #pragma unroll
            for (int j = 0; j < 4; j++) {
                bf16x8 bfv = *(const bf16x8*)&Bs[j * 16 + row16][kt * 32 + kg * 8];
                acc[j] = mfma_bf16(af, bfv, acc[j]);
            }
        }
        __syncthreads();
    }
    #pragma unroll
    for (int j = 0; j < 4; j++)
        #pragma unroll
        for (int r = 0; r < 4; r++)
            APo[(size_t)(m0 + w * 16 + kg * 4 + r) * 512 + n0 + j * 16 + row16] =
                (__bf16)acc[j][r];
}

// ---------------- persistent step-loop kernel (grid = 64 blocks) ----------------
// 2 barrier units/step (was 3):
//  A (all 64 blocks, unit slice = 8 units): gates GEMM + LSTM pointwise -> h,
//    PLUS h-part partial of the o-projection: ChP[blk][b][u] over this block's
//    8-k slice of Wu_h (8KB LDS-resident weight slice). f32 partials, sc1 stores.
//  BC (all 64 blocks, block = batch): attention (L2-affine AP[b]) + o =
//    tanh(sum_p ChP[p][b] + sum_r att[r]*LU[b][r] + bu). LU is the precomputed
//    LF@Wu_a^T (L2-affine 50KB/batch) -- no weight broadcast anywhere.
// CHP addresses are reused each step -> consumers use agent-scope atomic loads
// (L2-bypassing, always fresh from the coherence point after the barrier).
__global__ __launch_bounds__(256) void loop_kernel(
    const __bf16* Yall, const __bf16* WG, const float* BG,
    const __bf16* WhT, const float* bu,
    const __bf16* APb, const __bf16* LUb, const float* CF0,
    __bf16* OS, __bf16* HS, float* CHP, unsigned* FL)
{
    __shared__ float S[64][33];
    __shared__ float Cs[64][8];
    __shared__ float Hs[64][8];
    __shared__ __bf16 Ws[8][512];   // Wu_hT slice: k in [8*blk, 8*blk+8)
    __shared__ float esh[64];
    __shared__ float ash[64];
    int tid = threadIdx.x;
    int blk = blockIdx.x;
    int w = tid >> 6, lane = tid & 63, row16 = lane & 15, kg = lane >> 4;

    // stage Wu_hT slice (step-invariant, 8KB)
    for (int i = tid; i < 8 * 512; i += 256)
        Ws[i >> 9][i & 511] = WhT[(size_t)(blk * 8 + (i >> 9)) * 512 + (i & 511)];
    // load c0 slice (units [8*blk, 8*blk+8)) into LDS — block-local forever
    {
        int b = tid >> 2, u0 = (tid & 3) * 2;
        Cs[b][u0]     = CF0[b * 512 + blk * 8 + u0];
        Cs[b][u0 + 1] = CF0[b * 512 + blk * 8 + u0 + 1];
    }
    __syncthreads();

    unsigned bgen = 0;
    for (int t = 0; t < 32; t++) {
        // ---- Phase A: gates = [y|o|h] @ WG^T (wave = 16-batch m-tile, full K),
        //      LSTM pointwise -> h (sc1 to HS[t+1], f32 to LDS), c (LDS),
        //      then ChP h-part partials (sc1 f32) ----
        {
            const __bf16* Yt = Yall + t * 16384;
            const __bf16* Op = OS + t * 32768;
            const __bf16* Hp = HS + t * 32768;
            int n0 = blk * 32;
            f32x4 acc[2] = {};
            #pragma unroll
            for (int kt = 0; kt < 40; kt++) {
                int k0 = kt * 32;
                bf16x8 af;
                if (k0 < 256)      af = ldb8(Yt + (w * 16 + row16) * 256 + k0 + kg * 8);
                else if (k0 < 768) af = ldb8(Op + (w * 16 + row16) * 512 + (k0 - 256) + kg * 8);
                else               af = ldb8(Hp + (w * 16 + row16) * 512 + (k0 - 768) + kg * 8);
                #pragma unroll
                for (int nt = 0; nt < 2; nt++) {
                    bf16x8 bfv = ldb8(WG + (size_t)(n0 + nt * 16 + row16) * 1280 + k0 + kg * 8);
                    acc[nt] = mfma_bf16(af, bfv, acc[nt]);
                }
            }
            #pragma unroll
            for (int nt = 0; nt < 2; nt++)
                #pragma unroll
                for (int r = 0; r < 4; r++)
                    S[w * 16 + kg * 4 + r][nt * 16 + row16] = acc[nt][r];
            __syncthreads();
            {
                int b = tid >> 2, u0 = (tid & 3) * 2;
                float h2[2];
                #pragma unroll
                for (int uu = 0; uu < 2; uu++) {
                    int u = u0 + uu;
                    float gi = S[b][u * 4 + 0] + BG[n0 + u * 4 + 0];
                    float gf = S[b][u * 4 + 1] + BG[n0 + u * 4 + 1];
                    float gg = S[b][u * 4 + 2] + BG[n0 + u * 4 + 2];
                    float go = S[b][u * 4 + 3] + BG[n0 + u * 4 + 3];
                    float cp = Cs[b][u];
                    float cn = sigf(gf) * cp + sigf(gi) * tanhf(gg);
                    h2[uu] = sigf(go) * tanhf(cn);
                    Cs[b][u] = cn;
                }
                Hs[b][u0] = h2[0];
                Hs[b][u0 + 1] = h2[1];
                union { __bf16 h[2]; unsigned v; } pk;
                pk.h[0] = (__bf16)h2[0]; pk.h[1] = (__bf16)h2[1];
                stc_u32((unsigned*)(HS + (t + 1) * 32768 + b * 512 + blk * 8 + u0), pk.v);
            }
            __syncthreads();
            // ChP[blk][b][u] = sum_{k<8} Hs[b][k] * Ws[k][u]  (f32 partials)
            {
                int bh = tid >> 7;            // batch half
                int u0 = (tid & 127) * 4;     // 4 units per thread
                #pragma unroll 4
                for (int bb = 0; bb < 32; bb++) {
                    int b = bh * 32 + bb;
                    float a0 = 0.f, a1 = 0.f, a2 = 0.f, a3 = 0.f;
                    #pragma unroll
                    for (int k = 0; k < 8; k++) {
                        float hv = Hs[b][k];
                        bf16x4 wv = *(const bf16x4*)&Ws[k][u0];
                        a0 += hv * (float)wv[0]; a1 += hv * (float)wv[1];
                        a2 += hv * (float)wv[2]; a3 += hv * (float)wv[3];
                    }
                    union { float f[4]; unsigned long long q[2]; } pk;
                    pk.f[0] = a0; pk.f[1] = a1; pk.f[2] = a2; pk.f[3] = a3;
                    unsigned long long* dst =
                        (unsigned long long*)(CHP + ((size_t)blk * 64 + b) * 512 + u0);
                    stc_u64(dst, pk.q[0]);
                    stc_u64(dst + 1, pk.q[1]);
                }
            }
        }
        gbar_all(FL, blk, ++bgen);

        // ---- Phase BC (block = batch b = blk): attention + o-combine ----
        {
            int b = blk;
            const __bf16* hb = HS + (size_t)(t + 1) * 32768 + b * 512;
            bf16x8 h8 = ldb8(hb + lane * 8);
            // ChP sum first: issue the 64 independent L2-bypass 8B loads early
            float oh0 = 0.f, oh1 = 0.f;
            {
                float* cp = CHP + (size_t)b * 512 + tid * 2;
                #pragma unroll 16
                for (int p = 0; p < 64; p++) {
                    union { unsigned long long q; float f[2]; } c;
                    c.q = ldc_u64(cp + (size_t)p * 32768);
                    oh0 += c.f[0]; oh1 += c.f[1];
                }
            }
            // e[r] = attn_proj[b][r] . h
            for (int r = w; r < 49; r += 4) {
                bf16x8 ap8 = ldb8(APb + (size_t)(b * 49 + r) * 512 + lane * 8);
                float s = 0.f;
                #pragma unroll
                for (int u = 0; u < 8; u++) s += (float)ap8[u] * (float)h8[u];
                #pragma unroll
                for (int off = 32; off > 0; off >>= 1) s += __shfl_xor(s, off);
                if (lane == 0) esh[r] = s;
            }
            __syncthreads();
            if (tid < 64) {
                float v = (tid < 49) ? esh[tid] : -3.0e38f;
                float mx = v;
                #pragma unroll
                for (int off = 32; off > 0; off >>= 1) mx = fmaxf(mx, __shfl_xor(mx, off));
                float ex = (tid < 49) ? expf(v - mx) : 0.0f;
                float sm = ex;
                #pragma unroll
                for (int off = 32; off > 0; off >>= 1) sm += __shfl_xor(sm, off);
                if (tid < 49) ash[tid] = ex / sm;
            }
            __syncthreads();
            // a-part via LU: oa[u] = sum_r att[r] * LU[b][r][u]
            float oa0 = 0.f, oa1 = 0.f;
            {
                const __bf16* lu = LUb + (size_t)b * 49 * 512 + tid * 2;
                #pragma unroll 7
                for (int r = 0; r < 49; r++) {
                    float wt = ash[r];
                    union { unsigned u; __bf16 h[2]; } c;
                    c.u = *(const unsigned*)(lu + (size_t)r * 512);
                    oa0 += wt * (float)c.h[0];
                    oa1 += wt * (float)c.h[1];
                }
            }
            int u = tid * 2;
            float o0v = tanhf(oh0 + oa0 + bu[u]);
            float o1v = tanhf(oh1 + oa1 + bu[u + 1]);
            union { __bf16 h[2]; unsigned v; } pk;
            pk.h[0] = (__bf16)o0v; pk.h[1] = (__bf16)o1v;
            stc_u32((unsigned*)(OS + (size_t)(t + 1) * 32768 + b * 512 + u), pk.v);
        }
        gbar_all(FL, blk, ++bgen);
    }
}

// ---------------- vocab: logits = O @ Wv^T + b, 128x128 LDS-tiled MFMA ----------------
// B operand converted f32 -> bf16 during LDS staging (no WV buffer needed).
__global__ __launch_bounds__(256) void vocab_kernel(
    const __bf16* A, const float* Wv, const float* bv, float* out)
{
    __shared__ __bf16 As[128][72];
    __shared__ __bf16 Bs[128][72];
    int tid = threadIdx.x;
    int m0 = blockIdx.x * 128;   // 16 mblk
    int n0 = blockIdx.y * 128;   // 79 nblk
    int w = tid >> 6, lane = tid & 63, row16 = lane & 15, kg = lane >> 4;
    int mw = (w & 1) * 64, nw = (w >> 1) * 64;
    f32x4 acc[4][4] = {};
    for (int k0 = 0; k0 < 512; k0 += 64) {
        #pragma unroll
        for (int q = 0; q < 2; q++) {
            int c = q * 256 + tid;
            int r = c >> 2, col = (c & 3) * 16;
            bf16x8 v0 = ldb8(A + (size_t)(m0 + r) * 512 + k0 + col);
            bf16x8 v1 = ldb8(A + (size_t)(m0 + r) * 512 + k0 + col + 8);
            *(bf16x8*)&As[r][col] = v0;
            *(bf16x8*)&As[r][col + 8] = v1;
            bf16x8 u0, u1;
            int nrow = n0 + r;
            if (nrow < 10000) {
                const float* bp = Wv + (size_t)nrow * 512 + k0 + col;
                #pragma unroll
                for (int u = 0; u < 8; u++) {
                    u0[u] = (__bf16)bp[u];
                    u1[u] = (__bf16)bp[u + 8];
                }
            } else {
                u0 = (bf16x8)(__bf16)0.0f;
                u1 = (bf16x8)(__bf16)0.0f;
            }
            *(bf16x8*)&Bs[r][col] = u0;
            *(bf16x8*)&Bs[r][col + 8] = u1;
        }
        __syncthreads();
        #pragma unroll
        for (int kt = 0; kt < 2; kt++) {
            bf16x8 af[4], bfr[4];
            #pragma unroll
            for (int i = 0; i < 4; i++)
                af[i] = *(const bf16x8*)&As[mw + i * 16 + row16][kt * 32 + kg * 8];
            #pragma unroll
            for (int j = 0; j < 4; j++)
                bfr[j] = *(const bf16x8*)&Bs[nw + j * 16 + row16][kt * 32 + kg * 8];
            #pragma unroll
            for (int i = 0; i < 4; i++)
                #pragma unroll
                for (int j = 0; j < 4; j++)
                    acc[i][j] = mfma_bf16(af[i], bfr[j], acc[i][j]);
        }
        __syncthreads();
    }
    #pragma unroll
    for (int j = 0; j < 4; j++) {
        int n = n0 + nw + j * 16 + row16;
        if (n < 10000) {
            float bvn = bv[n];
            #pragma unroll
            for (int i = 0; i < 4; i++) {
                #pragma unroll
                for (int r = 0; r < 4; r++) {
                    int m = m0 + mw + i * 16 + kg * 4 + r;   // m = t*64 + b
                    int tt = m >> 6, b = m & 63;
                    out[(size_t)(b * 32 + tt) * 10000 + n] = acc[i][j][r] + bvn;
                }
            }
        }
    }
}

extern "C" void kernel_launch(void* const* d_in, const int* in_sizes, int n_in,
                              void* d_out, int out_size, void* d_ws, size_t ws_size,
                              hipStream_t stream) {
    (void)in_sizes; (void)n_in; (void)out_size; (void)ws_size;
    const float* localf  = (const float*)d_in[0];
    const float* globalf = (const float*)d_in[1];
    const float* qvec    = (const float*)d_in[2];
    const int*   answers = (const int*)d_in[3];
    const float* emb     = (const float*)d_in[4];
    const float* Wg2o    = (const float*)d_in[5];
    const float* bg2o    = (const float*)d_in[6];
    const float* Wh      = (const float*)d_in[7];
    const float* Wc      = (const float*)d_in[8];
    const float* Wih     = (const float*)d_in[9];
    const float* Whh     = (const float*)d_in[10];
    const float* bih     = (const float*)d_in[11];
    const float* bhh     = (const float*)d_in[12];
    const float* Wattn   = (const float*)d_in[13];
    const float* Wu      = (const float*)d_in[14];
    const float* bu      = (const float*)d_in[15];
    const float* Wvocab  = (const float*)d_in[16];
    const float* bvocab  = (const float*)d_in[17];
    float* out = (float*)d_out;

    char* ws = (char*)d_ws;
    __bf16* WG  = (__bf16*)(ws + 0);          // 2048*1280 bf16 (gate-perm [W_ih|W_hh])   5,242,880
    __bf16* WhT = (__bf16*)(ws + 5242880);    // 512*512 bf16 (Wu_h transposed)             524,288
    __bf16* Y   = (__bf16*)(ws + 5767168);    // 32*64*256 bf16                           1,048,576
    float*  BG  = (float*) (ws + 6815744);    // 2048 f32 (b_ih+b_hh perm)                    8,192
    __bf16* OS  = (__bf16*)(ws + 6823936);    // 33 slots * 64*512 bf16 (o; slot0=o0)     2,162,688
    __bf16* HS  = (__bf16*)(ws + 8986624);    // 33 slots * 64*512 bf16 (h; slot0=h0)     2,162,688
    float*  CF0 = (float*) (ws + 11149312);   // 64*512 f32 (c0)                            131,072
    __bf16* APb = (__bf16*)(ws + 11280384);   // 64*49*512 bf16 (attn_proj)               3,211,264
    __bf16* LUb = (__bf16*)(ws + 14491648);   // 64*49*512 bf16 (LF @ Wu_a^T)             3,211,264
    float*  CHP = (float*) (ws + 17702912);   // 64 blk * 64 b * 512 u f32 (h-part part.) 8,388,608
    unsigned* FL = (unsigned*)(ws + 26091520); // 64 u32 flags                                 256
    // total: 26,091,776 B  (within r1-verified >=27.5MB workspace)

    hipMemsetAsync(FL, 0, 256, stream);
    convert_kernel<<<dim3(1024, 1, 3), 256, 0, stream>>>(
        Wih, Whh, bih, bhh, Wu, emb, answers,
        WG, BG, WhT, Y);
    init_kernel<<<dim3(8, 4, 3), 256, 0, stream>>>(
        qvec, globalf, Wh, Wc, Wg2o, bg2o, HS, CF0, OS);
    attnproj_kernel<<<dim3(49, 8), 256, 0, stream>>>(localf, Wattn, 1024, APb);
    attnproj_kernel<<<dim3(49, 8), 256, 0, stream>>>(localf, Wu, 1536, LUb);
    loop_kernel<<<GRID_BLKS, 256, 0, stream>>>(
        Y, WG, BG, WhT, bu, APb, LUb, CF0, OS, HS, CHP, FL);
    vocab_kernel<<<dim3(16, 79), 256, 0, stream>>>(OS + 32768, Wvocab, bvocab, out);
}